// Round 7
// baseline (244.876 us; speedup 1.0000x reference)
//
#include <hip/hip_runtime.h>
#include <hip/hip_bf16.h>

#define BB 32
#define NN 4096
#define DDIM 64
#define NCH 8

typedef __attribute__((ext_vector_type(8)))  short bf16x8;
typedef __attribute__((ext_vector_type(16))) float f32x16;
typedef __attribute__((ext_vector_type(4)))  float f32x4;

// packed fp32x2 -> bf16x2 (RNE, v_cvt_pk_bf16_f32 on gfx950)
static __device__ inline unsigned pk(float a, float b) {
  union { __hip_bfloat162 h; unsigned u; } c;
  c.h = __float22bfloat162_rn(float2{a, b});
  return c.u;
}

static __device__ inline bf16x8 pack8(const float* f) {
  union { unsigned u[4]; bf16x8 v; } r;
  r.u[0] = pk(f[0], f[1]); r.u[1] = pk(f[2], f[3]);
  r.u[2] = pk(f[4], f[5]); r.u[3] = pk(f[6], f[7]);
  return r.v;
}

// ---------------------------------------------------------------------------
// proj_gemm v6 (FROZEN from r6): 512-thread LDS-staged pipeline.
// ---------------------------------------------------------------------------
template <int MAT>
static __device__ inline void proj_core6(
    const float* __restrict__ Gbig,   // [NN][256] (E or F)
    const float* __restrict__ Gsml,   // [NN][64]  (K[b] or V[b])
    float* __restrict__ Cg,           // fp32 partial out for this (b,chunk)
    unsigned short (*lds)[10240], int chunk)
{
  const int t = threadIdx.x;                 // 0..511
  const int w = t >> 6, l = t & 63, h = l >> 5, lr = l & 31;
  const int hs = t >> 8;                     // BIG row-half selector (0/1)
  const int colB = t & 255;                  // BIG col
  const int gS = (t >> 6) & 3;               // SML octet (t<256)
  const int colS = t & 63;                   // SML col

  const int n00 = chunk * 512;               // 512-n chunk, T=16 steps of 32

  f32x16 acc[2];
#pragma unroll
  for (int j = 0; j < 2; ++j)
#pragma unroll
    for (int q = 0; q < 16; ++q) acc[j][q] = 0.f;

  float xb[16], xs[8], yb[16], ys[8];

  auto loadset = [&](float (&vb)[16], float (&vs)[8], int step) {
    const float* qb = Gbig + (long)(n00 + step * 32 + hs * 16) * 256 + colB;
#pragma unroll
    for (int i = 0; i < 16; ++i) vb[i] = qb[(long)i * 256];
    if (t < 256) {
      const float* qs = Gsml + (long)(n00 + step * 32 + gS * 8) * 64 + colS;
#pragma unroll
      for (int j = 0; j < 8; ++j) vs[j] = qs[(long)j * 64];
    }
  };

  auto writeset = [&](int buf, float (&vb)[16], float (&vs)[8]) {
#pragma unroll
    for (int gg = 0; gg < 2; ++gg) {
      const int g = hs * 2 + gg;
      *(bf16x8*)&lds[buf][(g * 256 + colB) * 8] = pack8(&vb[gg * 8]);
    }
    if (t < 256)
      *(bf16x8*)&lds[buf][8192 + (gS * 64 + colS) * 8] = pack8(vs);
  };

  auto consume = [&](int buf) {
#pragma unroll
    for (int s2 = 0; s2 < 2; ++s2) {
      const int g = s2 * 2 + h;              // lane's K-octet
      bf16x8 Bg = *(const bf16x8*)&lds[buf][(g * 256 + w * 32 + lr) * 8];
      bf16x8 S0 = *(const bf16x8*)&lds[buf][8192 + (g * 64 + lr) * 8];
      bf16x8 S1 = *(const bf16x8*)&lds[buf][8192 + (g * 64 + 32 + lr) * 8];
      if (MAT == 0) {
        acc[0] = __builtin_amdgcn_mfma_f32_32x32x16_bf16(Bg, S0, acc[0], 0, 0, 0);
        acc[1] = __builtin_amdgcn_mfma_f32_32x32x16_bf16(Bg, S1, acc[1], 0, 0, 0);
      } else {
        acc[0] = __builtin_amdgcn_mfma_f32_32x32x16_bf16(S0, Bg, acc[0], 0, 0, 0);
        acc[1] = __builtin_amdgcn_mfma_f32_32x32x16_bf16(S1, Bg, acc[1], 0, 0, 0);
      }
    }
  };

  loadset(xb, xs, 0);
  loadset(yb, ys, 1);

#pragma unroll 1
  for (int tt = 0; tt < 16; tt += 2) {
    writeset(0, xb, xs);
    if (tt + 2 < 16) loadset(xb, xs, tt + 2);
    __syncthreads();
    consume(0);
    writeset(1, yb, ys);
    if (tt + 3 < 16) loadset(yb, ys, tt + 3);
    __syncthreads();
    consume(1);
  }

#pragma unroll
  for (int j = 0; j < 2; ++j)
#pragma unroll
    for (int i = 0; i < 16; ++i) {
      const int ro = (i & 3) + 8 * (i >> 2) + 4 * h;   // C/D row map (32x32)
      if (MAT == 0) {
        const int row = w * 32 + ro;                   // k
        const int col = j * 32 + lr;                   // d
        Cg[row * 64 + col] = acc[j][i];
      } else {
        const int row = j * 32 + ro;                   // d
        const int col = w * 32 + lr;                   // k
        Cg[row * 256 + col] = acc[j][i];
      }
    }
}

__global__ __launch_bounds__(512, 4) void proj_gemm(
    const float* __restrict__ Kg, const float* __restrict__ Vg,
    const float* __restrict__ Eg, const float* __restrict__ Fg,
    float* __restrict__ KpP, float* __restrict__ VpP)
{
  __shared__ unsigned short lds[2][10240];             // 40 KB

  const int blk = blockIdx.x;
  const int chunk = blk % NCH;
  const int mat = (blk / NCH) & 1, b = blk / (2 * NCH);
  const long PSTR = (long)BB * 16384;

  if (mat == 0) {
    proj_core6<0>(Eg, Kg + (long)b * NN * DDIM,
                  KpP + (long)chunk * PSTR + b * 16384, lds, chunk);
  } else {
    proj_core6<1>(Fg, Vg + (long)b * NN * DDIM,
                  VpP + (long)chunk * PSTR + b * 16384, lds, chunk);
  }
}

// ---------------------------------------------------------------------------
// reduce_cvt (FROZEN from r6): sum NCH fp32 partials -> bf16, grid 1024.
// ---------------------------------------------------------------------------
__global__ __launch_bounds__(256) void reduce_cvt(
    const float* __restrict__ KpP, const float* __restrict__ VpP,
    unsigned short* __restrict__ Kpb, unsigned short* __restrict__ Vpb)
{
  const int blk = blockIdx.x;
  const float* src = (blk < 512) ? KpP : VpP;
  unsigned short* dst = (blk < 512) ? Kpb : Vpb;
  const long i = (long)(blk & 511) * 1024 + threadIdx.x * 4;
  float a0 = 0.f, a1 = 0.f, a2 = 0.f, a3 = 0.f;
#pragma unroll
  for (int cch = 0; cch < NCH; ++cch) {
    const float4 p = *(const float4*)(src + (long)cch * (BB * 16384) + i);
    a0 += p.x; a1 += p.y; a2 += p.z; a3 += p.w;
  }
  uint2 o;
  o.x = pk(a0, a1); o.y = pk(a2, a3);
  *(uint2*)(dst + i) = o;
}

// ---------------------------------------------------------------------------
// attn2 v5: 2-row-tile structure (41-us baseline shape) + software-pipelined
// kt loop. Named A/B register frag buffers, FULLY UNROLLED kt, and
// sched_barrier(0) pinning so the 8 loads for kt+1 are ISSUED before unit
// kt's compute (r1-r6 lesson: compiler sinks unpinned prefetch to its use,
// exposing full L2 latency inside the serial chain every iteration).
// exp2 via native intrinsic. launch_bounds(256,2): VGPR headroom for the
// double buffer (grid caps occupancy at 2 blocks/CU regardless).
// ---------------------------------------------------------------------------
__global__ __launch_bounds__(256, 2) void attn2_kernel(
    const float* __restrict__ Qg, const unsigned short* __restrict__ Kpb,
    const unsigned short* __restrict__ Vpb, float* __restrict__ Og)
{
  extern __shared__ float O_lds[];          // 256 x 64 fp32 = 64 KB

  const int blk = blockIdx.x;
  const int b = blk >> 4, rg = blk & 15;
  const int t = threadIdx.x, w = t >> 6, l = t & 63;
  const int h = l >> 5, lr = l & 31;
  const int rbase = rg * 256 + w * 64;

  const unsigned short* Kp = Kpb + (long)b * 16384;   // [k=256][d=64]
  const unsigned short* Vp = Vpb + (long)b * 16384;   // [d=64][k=256]

  // ---- Q B-frags for 2 row-tiles: B[n=r(lane lr)][k=d contiguous]
  bf16x8 Bq[2][4];
#pragma unroll
  for (int rt = 0; rt < 2; ++rt)
#pragma unroll
    for (int kk = 0; kk < 4; ++kk) {
      const float* qp = Qg + ((long)b * NN + rbase + rt * 32 + lr) * 64 + kk * 16 + h * 8;
      float4 x = *(const float4*)qp;
      float4 y = *(const float4*)(qp + 4);
      union { unsigned u[4]; bf16x8 v; } r;
      r.u[0] = pk(x.x, x.y); r.u[1] = pk(x.z, x.w);
      r.u[2] = pk(y.x, y.y); r.u[3] = pk(y.z, y.w);
      Bq[rt][kk] = r.v;
    }

  f32x16 o[2][2];                           // [row-tile][d-tile]
#pragma unroll
  for (int rt = 0; rt < 2; ++rt)
#pragma unroll
    for (int dt = 0; dt < 2; ++dt)
#pragma unroll
      for (int q = 0; q < 16; ++q) o[rt][dt][q] = 0.f;
  float rowpart[2] = {0.f, 0.f};

  union UV { uint4 u; bf16x8 v; };

  // frag loads for one kt: Ak[4] (Kp rows), Av[4] = [dt*2+kc] (Vp rows)
  auto LDK = [&](int kt, bf16x8 (&Ak)[4], bf16x8 (&Av)[4]) {
#pragma unroll
    for (int kk = 0; kk < 4; ++kk)
      Ak[kk] = *(const bf16x8*)(Kp + (long)(kt * 32 + lr) * 64 + kk * 16 + h * 8);
#pragma unroll
    for (int dt = 0; dt < 2; ++dt)
#pragma unroll
      for (int kc = 0; kc < 2; ++kc)
        Av[dt * 2 + kc] = *(const bf16x8*)(Vp + (long)(dt * 32 + lr) * 256 + (kt * 2 + kc) * 16 + h * 8);
  };

  // one kt unit: QK^T MFMA -> exp2 -> pack -> half-wave exchange -> PV
  auto UNIT = [&](bf16x8 (&Ak)[4], bf16x8 (&Av)[4]) {
#pragma unroll
    for (int rt = 0; rt < 2; ++rt) {
      f32x16 s;
#pragma unroll
      for (int q = 0; q < 16; ++q) s[q] = 0.f;
#pragma unroll
      for (int kk = 0; kk < 4; ++kk)
        s = __builtin_amdgcn_mfma_f32_32x32x16_bf16(Ak[kk], Bq[rt][kk], s, 0, 0, 0);

      float p[16];
#pragma unroll
      for (int q = 0; q < 16; ++q)
        p[q] = __builtin_amdgcn_exp2f(s[q] * 0.1803368801f);  // exp(s/8)
      rowpart[rt] += (((p[0] + p[1]) + (p[2] + p[3])) + ((p[4] + p[5]) + (p[6] + p[7])))
                   + (((p[8] + p[9]) + (p[10] + p[11])) + ((p[12] + p[13]) + (p[14] + p[15])));

      unsigned wv[8];
#pragma unroll
      for (int m = 0; m < 8; ++m) wv[m] = pk(p[2 * m], p[2 * m + 1]);
      // half-wave exchange: C-layout k=(q&3)+8(q>>2)+4h -> B-layout k=h*8+j
      unsigned r02 = __shfl_xor(h ? wv[0] : wv[2], 32);
      unsigned r13 = __shfl_xor(h ? wv[1] : wv[3], 32);
      unsigned r46 = __shfl_xor(h ? wv[4] : wv[6], 32);
      unsigned r57 = __shfl_xor(h ? wv[5] : wv[7], 32);
      UV c0, c1;
      if (h == 0) {
        c0.u = uint4{wv[0], wv[1], r02, r13};
        c1.u = uint4{wv[4], wv[5], r46, r57};
      } else {
        c0.u = uint4{r02, r13, wv[2], wv[3]};
        c1.u = uint4{r46, r57, wv[6], wv[7]};
      }
      o[rt][0] = __builtin_amdgcn_mfma_f32_32x32x16_bf16(Av[0], c0.v, o[rt][0], 0, 0, 0);
      o[rt][0] = __builtin_amdgcn_mfma_f32_32x32x16_bf16(Av[1], c1.v, o[rt][0], 0, 0, 0);
      o[rt][1] = __builtin_amdgcn_mfma_f32_32x32x16_bf16(Av[2], c0.v, o[rt][1], 0, 0, 0);
      o[rt][1] = __builtin_amdgcn_mfma_f32_32x32x16_bf16(Av[3], c1.v, o[rt][1], 0, 0, 0);
    }
  };

  bf16x8 AkA[4], AvA[4], AkB[4], AvB[4];
  LDK(0, AkA, AvA);

#pragma unroll
  for (int kt = 0; kt < 8; kt += 2) {
    if (kt + 1 < 8) LDK(kt + 1, AkB, AvB);   // issue-ahead for next unit
    __builtin_amdgcn_sched_barrier(0);       // pin: loads issued BEFORE compute
    UNIT(AkA, AvA);
    if (kt + 2 < 8) LDK(kt + 2, AkA, AvA);
    __builtin_amdgcn_sched_barrier(0);
    UNIT(AkB, AvB);
  }

  // ---- normalize (rowsum at lane=row) and transpose via swizzled LDS
#pragma unroll
  for (int rt = 0; rt < 2; ++rt) {
    float rowsum = rowpart[rt] + __shfl_xor(rowpart[rt], 32);
    float inv = __builtin_amdgcn_rcpf(rowsum);
    const int r = w * 64 + rt * 32 + lr;
#pragma unroll
    for (int dt = 0; dt < 2; ++dt)
#pragma unroll
      for (int qg = 0; qg < 4; ++qg) {
        f32x4 vq;
        vq[0] = o[rt][dt][qg * 4 + 0] * inv;
        vq[1] = o[rt][dt][qg * 4 + 1] * inv;
        vq[2] = o[rt][dt][qg * 4 + 2] * inv;
        vq[3] = o[rt][dt][qg * 4 + 3] * inv;
        int cd = dt * 8 + 2 * qg + h;        // d-chunk (4 dwords)
        int cp = cd ^ (r & 15);              // XOR swizzle
        *(f32x4*)&O_lds[r * 64 + cp * 4] = vq;
      }
  }
  __syncthreads();

  const long obase = ((long)b * NN + rg * 256) * 64;
#pragma unroll
  for (int i = 0; i < 16; ++i) {
    int ci = i * 256 + t;
    int rr = ci >> 4, cc = ci & 15, cp = cc ^ (rr & 15);
    *(float4*)(Og + obase + rr * 64 + cc * 4) = *(const float4*)&O_lds[rr * 64 + cp * 4];
  }
}

extern "C" void kernel_launch(void* const* d_in, const int* in_sizes, int n_in,
                              void* d_out, int out_size, void* d_ws, size_t ws_size,
                              hipStream_t stream) {
  const float* Q = (const float*)d_in[0];
  const float* K = (const float*)d_in[1];
  const float* V = (const float*)d_in[2];
  const float* E = (const float*)d_in[3];
  const float* F = (const float*)d_in[4];
  float* out = (float*)d_out;

  // workspace layout (34 MB)
  char* ws = (char*)d_ws;
  float*          KpP = (float*)(ws);                          // 16 MB (8 partial chunks)
  float*          VpP = (float*)(ws + (16l << 20));            // 16 MB
  unsigned short* Kpb = (unsigned short*)(ws + (32l << 20));   // 1 MB
  unsigned short* Vpb = (unsigned short*)(ws + (33l << 20));   // 1 MB

  hipFuncSetAttribute((const void*)attn2_kernel,
                      hipFuncAttributeMaxDynamicSharedMemorySize, 65536);

  proj_gemm<<<dim3(512), dim3(512), 0, stream>>>(K, V, E, F, KpP, VpP);

  reduce_cvt<<<dim3(1024), dim3(256), 0, stream>>>(KpP, VpP, Kpb, Vpb);

  attn2_kernel<<<dim3(512), dim3(256), 65536, stream>>>(Q, Kpb, Vpb, out);
}

// Round 8
// 192.910 us; speedup vs baseline: 1.2694x; 1.2694x over previous
//
#include <hip/hip_runtime.h>
#include <hip/hip_bf16.h>

#define BB 32
#define NN 4096
#define DDIM 64
#define NCH 8

typedef __attribute__((ext_vector_type(8)))  short bf16x8;
typedef __attribute__((ext_vector_type(16))) float f32x16;
typedef __attribute__((ext_vector_type(4)))  float f32x4;

// packed fp32x2 -> bf16x2 (RNE, v_cvt_pk_bf16_f32 on gfx950)
static __device__ inline unsigned pk(float a, float b) {
  union { __hip_bfloat162 h; unsigned u; } c;
  c.h = __float22bfloat162_rn(float2{a, b});
  return c.u;
}

static __device__ inline bf16x8 pack8(const float* f) {
  union { unsigned u[4]; bf16x8 v; } r;
  r.u[0] = pk(f[0], f[1]); r.u[1] = pk(f[2], f[3]);
  r.u[2] = pk(f[4], f[5]); r.u[3] = pk(f[6], f[7]);
  return r.v;
}

// HBM -> LDS direct DMA, 16B per lane. LDS dest = wave-uniform base
// (+ lane*16 applied by HW); global src is per-lane.
static __device__ __forceinline__ void dma16(const float* g, float* l) {
  __builtin_amdgcn_global_load_lds(
      (const __attribute__((address_space(1))) void*)g,
      (__attribute__((address_space(3))) void*)l, 16, 0, 0);
}

// ---------------------------------------------------------------------------
// proj_gemm v7: ZERO-REGISTER staging via global_load_lds + counted vmcnt.
// Session finding: every register-staged version (r0-r6) was stuck at ~41us
// because 40 in-flight scalar loads need 40 dest VGPRs the allocator can't
// afford -> loads serialize into latency-gated clusters. DMA staging has no
// dest registers: 3-buffer LDS rotation, 5 issues/wave/step, s_waitcnt
// vmcnt(5) (never 0 mid-loop) + one raw s_barrier per step.
// Tiles are contiguous in global (E/F/K/V rows row-major) -> linear DMA OK.
// fp32 in LDS; bf16 pack moved to consume (b32 reads, 2-way alias = free).
// Race safety (3 buffers): issue(t+2) overwrites buf consumed at t-1; every
// wave passed barrier_t only after its consume(t-1) reads retired (register
// deps force the lgkm drain before the MFMAs that precede the barrier).
//   mat=0: Kp[k][d] = sum_n E[n][k] K[b][n][d]   (A=BIG(E),  B=SML(K))
//   mat=1: Vp[d][k] = sum_n V[b][n][d] F[n][k]   (A=SML(V), B=BIG(F))
// ---------------------------------------------------------------------------
template <int MAT>
static __device__ inline void proj_core7(
    const float* __restrict__ Gbig,   // [NN][256] (E or F)
    const float* __restrict__ Gsml,   // [NN][64]  (K[b] or V[b])
    float* __restrict__ Cg,           // fp32 partial out for this (b,chunk)
    float (*Bs)[4096], float (*Ss)[1024], int chunk)
{
  const int t = threadIdx.x, w = t >> 6, l = t & 63, h = l >> 5, lr = l & 31;

  const float* pbB = Gbig + (long)(chunk * 512) * 256;
  const float* pbS = Gsml + (long)(chunk * 512) * 64;

  f32x16 acc[2][2];
#pragma unroll
  for (int i = 0; i < 2; ++i)
#pragma unroll
    for (int j = 0; j < 2; ++j)
#pragma unroll
      for (int q = 0; q < 16; ++q) acc[i][j][q] = 0.f;

  // one 16-n step: BIG tile 16KB (4 issues/wave), SML tile 4KB (1 issue/wave)
  auto issue = [&](int step, int buf) {
    const float* gb = pbB + (long)step * (16 * 256) + w * 1024 + l * 4;
    float* lb = &Bs[buf][w * 1024];                 // wave-uniform LDS base
#pragma unroll
    for (int i = 0; i < 4; ++i)
      dma16(gb + i * 256, lb + i * 256);
    dma16(pbS + (long)step * (16 * 64) + w * 256 + l * 4, &Ss[buf][w * 256]);
  };

  auto consume = [&](int buf) {
    float fB0[8], fB1[8], fS0[8], fS1[8];
#pragma unroll
    for (int j = 0; j < 8; ++j) {
      const int rB = (h * 8 + j) * 256 + w * 64 + lr;   // [n][col] row-major
      const int rS = (h * 8 + j) * 64 + lr;
      fB0[j] = Bs[buf][rB];  fB1[j] = Bs[buf][rB + 32];
      fS0[j] = Ss[buf][rS];  fS1[j] = Ss[buf][rS + 32];
    }
    bf16x8 B0 = pack8(fB0), B1 = pack8(fB1);
    bf16x8 S0 = pack8(fS0), S1 = pack8(fS1);
    if (MAT == 0) {   // A = BIG (m=k, wave-split 4x64), B = SML (n=d)
      acc[0][0] = __builtin_amdgcn_mfma_f32_32x32x16_bf16(B0, S0, acc[0][0], 0, 0, 0);
      acc[0][1] = __builtin_amdgcn_mfma_f32_32x32x16_bf16(B0, S1, acc[0][1], 0, 0, 0);
      acc[1][0] = __builtin_amdgcn_mfma_f32_32x32x16_bf16(B1, S0, acc[1][0], 0, 0, 0);
      acc[1][1] = __builtin_amdgcn_mfma_f32_32x32x16_bf16(B1, S1, acc[1][1], 0, 0, 0);
    } else {          // A = SML (m=d), B = BIG (n=k, wave-split 4x64)
      acc[0][0] = __builtin_amdgcn_mfma_f32_32x32x16_bf16(S0, B0, acc[0][0], 0, 0, 0);
      acc[0][1] = __builtin_amdgcn_mfma_f32_32x32x16_bf16(S0, B1, acc[0][1], 0, 0, 0);
      acc[1][0] = __builtin_amdgcn_mfma_f32_32x32x16_bf16(S1, B0, acc[1][0], 0, 0, 0);
      acc[1][1] = __builtin_amdgcn_mfma_f32_32x32x16_bf16(S1, B1, acc[1][1], 0, 0, 0);
    }
  };

  issue(0, 0);
  issue(1, 1);

  int buf = 0;
#pragma unroll 1
  for (int tt = 0; tt < 32; ++tt) {
    // counted wait: oldest 5 (this step's DMAs) landed; next step stays in flight
    if (tt < 31) asm volatile("s_waitcnt vmcnt(5)" ::: "memory");
    else         asm volatile("s_waitcnt vmcnt(0)" ::: "memory");
    __builtin_amdgcn_s_barrier();
    __builtin_amdgcn_sched_barrier(0);       // reads must not hoist above barrier
    consume(buf);
    if (tt + 2 < 32) {
      int nb = buf + 2; if (nb >= 3) nb -= 3;
      issue(tt + 2, nb);
    }
    buf = (buf == 2) ? 0 : buf + 1;
  }

  const int mAdd = (MAT == 0) ? w * 64 : 0;
  const int nAdd = (MAT == 0) ? 0 : w * 64;
  const int OS   = (MAT == 0) ? 64 : 256;
#pragma unroll
  for (int mt = 0; mt < 2; ++mt)
#pragma unroll
    for (int nt = 0; nt < 2; ++nt)
#pragma unroll
      for (int i = 0; i < 16; ++i) {
        int ro  = (i & 3) + 8 * (i >> 2) + 4 * h;       // C/D row map
        int row = mAdd + mt * 32 + ro;
        int col = nAdd + nt * 32 + lr;
        Cg[row * OS + col] = acc[mt][nt][i];
      }
}

__global__ __launch_bounds__(256, 2) void proj_gemm(
    const float* __restrict__ Kg, const float* __restrict__ Vg,
    const float* __restrict__ Eg, const float* __restrict__ Fg,
    float* __restrict__ KpP, float* __restrict__ VpP)
{
  __shared__ float Bs[3][4096];              // 48 KB: BIG tiles (fp32)
  __shared__ float Ss[3][1024];              // 12 KB: SML tiles (fp32)

  const int blk = blockIdx.x;
  const int chunk = blk % NCH;               // chunk ~ XCD id -> E/F chunk L2-pinned
  const int mat = (blk / NCH) & 1, b = blk / (2 * NCH);
  const long PSTR = (long)BB * 16384;

  if (mat == 0) {
    proj_core7<0>(Eg, Kg + (long)b * NN * DDIM,
                  KpP + (long)chunk * PSTR + b * 16384, Bs, Ss, chunk);
  } else {
    proj_core7<1>(Fg, Vg + (long)b * NN * DDIM,
                  VpP + (long)chunk * PSTR + b * 16384, Bs, Ss, chunk);
  }
}

// ---------------------------------------------------------------------------
// reduce_cvt (FROZEN from r6): sum NCH fp32 partials -> bf16, grid 1024.
// ---------------------------------------------------------------------------
__global__ __launch_bounds__(256) void reduce_cvt(
    const float* __restrict__ KpP, const float* __restrict__ VpP,
    unsigned short* __restrict__ Kpb, unsigned short* __restrict__ Vpb)
{
  const int blk = blockIdx.x;
  const float* src = (blk < 512) ? KpP : VpP;
  unsigned short* dst = (blk < 512) ? Kpb : Vpb;
  const long i = (long)(blk & 511) * 1024 + threadIdx.x * 4;
  float a0 = 0.f, a1 = 0.f, a2 = 0.f, a3 = 0.f;
#pragma unroll
  for (int cch = 0; cch < NCH; ++cch) {
    const float4 p = *(const float4*)(src + (long)cch * (BB * 16384) + i);
    a0 += p.x; a1 += p.y; a2 += p.z; a3 += p.w;
  }
  uint2 o;
  o.x = pk(a0, a1); o.y = pk(a2, a3);
  *(uint2*)(dst + i) = o;
}

// ---------------------------------------------------------------------------
// attn2 (REVERTED to the proven 40.7us r1 version, verbatim): r7's pinned
// double-buffer spilled ~240 MB to scratch (VGPR 128 < needed ~190).
// ---------------------------------------------------------------------------
__global__ __launch_bounds__(256, 2) void attn2_kernel(
    const float* __restrict__ Qg, const unsigned short* __restrict__ Kpb,
    const unsigned short* __restrict__ Vpb, float* __restrict__ Og)
{
  extern __shared__ float O_lds[];          // 256 x 64 fp32 = 64 KB

  const int blk = blockIdx.x;
  const int b = blk >> 4, rg = blk & 15;
  const int t = threadIdx.x, w = t >> 6, l = t & 63;
  const int h = l >> 5, lr = l & 31;
  const int rbase = rg * 256 + w * 64;

  const unsigned short* Kp = Kpb + (long)b * 16384;   // [k=256][d=64]
  const unsigned short* Vp = Vpb + (long)b * 16384;   // [d=64][k=256]

  // ---- Q B-frags for 2 row-tiles: B[n=r(lane lr)][k=d contiguous]
  bf16x8 Bq[2][4];
#pragma unroll
  for (int rt = 0; rt < 2; ++rt)
#pragma unroll
    for (int kk = 0; kk < 4; ++kk) {
      const float* qp = Qg + ((long)b * NN + rbase + rt * 32 + lr) * 64 + kk * 16 + h * 8;
      float4 x = *(const float4*)qp;
      float4 y = *(const float4*)(qp + 4);
      union { unsigned u[4]; bf16x8 v; } r;
      r.u[0] = pk(x.x, x.y); r.u[1] = pk(x.z, x.w);
      r.u[2] = pk(y.x, y.y); r.u[3] = pk(y.z, y.w);
      Bq[rt][kk] = r.v;
    }

  f32x16 o[2][2];                           // [row-tile][d-tile]
#pragma unroll
  for (int rt = 0; rt < 2; ++rt)
#pragma unroll
    for (int dt = 0; dt < 2; ++dt)
#pragma unroll
      for (int q = 0; q < 16; ++q) o[rt][dt][q] = 0.f;
  float rowpart[2] = {0.f, 0.f};

  union UV { uint4 u; bf16x8 v; };

#pragma unroll
  for (int kt = 0; kt < 8; ++kt) {
    // Kp A-frags (shared by both row-tiles): A[m=k][d contiguous]
    bf16x8 Ak[4];
#pragma unroll
    for (int kk = 0; kk < 4; ++kk)
      Ak[kk] = *(const bf16x8*)(Kp + (long)(kt * 32 + lr) * 64 + kk * 16 + h * 8);
    // Vp A-frags for this k-chunk pair: A[m=d][k contiguous]
    bf16x8 Av[2][2];
#pragma unroll
    for (int dt = 0; dt < 2; ++dt)
#pragma unroll
      for (int kc = 0; kc < 2; ++kc)
        Av[dt][kc] = *(const bf16x8*)(Vp + (long)(dt * 32 + lr) * 256 + (kt * 2 + kc) * 16 + h * 8);

#pragma unroll
    for (int rt = 0; rt < 2; ++rt) {
      f32x16 s;
#pragma unroll
      for (int q = 0; q < 16; ++q) s[q] = 0.f;
#pragma unroll
      for (int kk = 0; kk < 4; ++kk)
        s = __builtin_amdgcn_mfma_f32_32x32x16_bf16(Ak[kk], Bq[rt][kk], s, 0, 0, 0);

      // exp(s/8) = exp2(s*log2(e)/8); no max-subtract (fp32-safe)
      float p[16];
#pragma unroll
      for (int q = 0; q < 16; ++q) p[q] = exp2f(s[q] * 0.1803368801f);
      rowpart[rt] += (((p[0] + p[1]) + (p[2] + p[3])) + ((p[4] + p[5]) + (p[6] + p[7])))
                   + (((p[8] + p[9]) + (p[10] + p[11])) + ((p[12] + p[13]) + (p[14] + p[15])));

      unsigned wv[8];
#pragma unroll
      for (int m = 0; m < 8; ++m) wv[m] = pk(p[2 * m], p[2 * m + 1]);
      // half-wave exchange: C-layout k=(q&3)+8(q>>2)+4h -> B-layout k=h*8+j
      unsigned r02 = __shfl_xor(h ? wv[0] : wv[2], 32);
      unsigned r13 = __shfl_xor(h ? wv[1] : wv[3], 32);
      unsigned r46 = __shfl_xor(h ? wv[4] : wv[6], 32);
      unsigned r57 = __shfl_xor(h ? wv[5] : wv[7], 32);
      UV c0, c1;
      if (h == 0) {
        c0.u = uint4{wv[0], wv[1], r02, r13};
        c1.u = uint4{wv[4], wv[5], r46, r57};
      } else {
        c0.u = uint4{r02, r13, wv[2], wv[3]};
        c1.u = uint4{r46, r57, wv[6], wv[7]};
      }
      // incremental PV: consume immediately, nothing stays live
      o[rt][0] = __builtin_amdgcn_mfma_f32_32x32x16_bf16(Av[0][0], c0.v, o[rt][0], 0, 0, 0);
      o[rt][0] = __builtin_amdgcn_mfma_f32_32x32x16_bf16(Av[0][1], c1.v, o[rt][0], 0, 0, 0);
      o[rt][1] = __builtin_amdgcn_mfma_f32_32x32x16_bf16(Av[1][0], c0.v, o[rt][1], 0, 0, 0);
      o[rt][1] = __builtin_amdgcn_mfma_f32_32x32x16_bf16(Av[1][1], c1.v, o[rt][1], 0, 0, 0);
    }
  }

  // ---- normalize (rowsum at lane=row) and transpose via swizzled LDS
#pragma unroll
  for (int rt = 0; rt < 2; ++rt) {
    float rowsum = rowpart[rt] + __shfl_xor(rowpart[rt], 32);
    float inv = __builtin_amdgcn_rcpf(rowsum);
    const int r = w * 64 + rt * 32 + lr;
#pragma unroll
    for (int dt = 0; dt < 2; ++dt)
#pragma unroll
      for (int qg = 0; qg < 4; ++qg) {
        f32x4 vq;
        vq[0] = o[rt][dt][qg * 4 + 0] * inv;
        vq[1] = o[rt][dt][qg * 4 + 1] * inv;
        vq[2] = o[rt][dt][qg * 4 + 2] * inv;
        vq[3] = o[rt][dt][qg * 4 + 3] * inv;
        int cd = dt * 8 + 2 * qg + h;        // d-chunk (4 dwords)
        int cp = cd ^ (r & 15);              // XOR swizzle
        *(f32x4*)&O_lds[r * 64 + cp * 4] = vq;
      }
  }
  __syncthreads();

  const long obase = ((long)b * NN + rg * 256) * 64;
#pragma unroll
  for (int i = 0; i < 16; ++i) {
    int ci = i * 256 + t;
    int rr = ci >> 4, cc = ci & 15, cp = cc ^ (rr & 15);
    *(float4*)(Og + obase + rr * 64 + cc * 4) = *(const float4*)&O_lds[rr * 64 + cp * 4];
  }
}

extern "C" void kernel_launch(void* const* d_in, const int* in_sizes, int n_in,
                              void* d_out, int out_size, void* d_ws, size_t ws_size,
                              hipStream_t stream) {
  const float* Q = (const float*)d_in[0];
  const float* K = (const float*)d_in[1];
  const float* V = (const float*)d_in[2];
  const float* E = (const float*)d_in[3];
  const float* F = (const float*)d_in[4];
  float* out = (float*)d_out;

  // workspace layout (34 MB)
  char* ws = (char*)d_ws;
  float*          KpP = (float*)(ws);                          // 16 MB (8 partial chunks)
  float*          VpP = (float*)(ws + (16l << 20));            // 16 MB
  unsigned short* Kpb = (unsigned short*)(ws + (32l << 20));   // 1 MB
  unsigned short* Vpb = (unsigned short*)(ws + (33l << 20));   // 1 MB

  hipFuncSetAttribute((const void*)attn2_kernel,
                      hipFuncAttributeMaxDynamicSharedMemorySize, 65536);

  proj_gemm<<<dim3(512), dim3(256), 0, stream>>>(K, V, E, F, KpP, VpP);

  reduce_cvt<<<dim3(1024), dim3(256), 0, stream>>>(KpP, VpP, Kpb, Vpb);

  attn2_kernel<<<dim3(512), dim3(256), 65536, stream>>>(Q, Kpb, Vpb, out);
}